// Round 7
// baseline (1768.289 us; speedup 1.0000x reference)
//
#include <hip/hip_runtime.h>

typedef unsigned short u16;
typedef short bf16x8 __attribute__((ext_vector_type(8)));
typedef float f32x4 __attribute__((ext_vector_type(4)));
typedef u16 u16x8 __attribute__((ext_vector_type(8)));

#define SLABH 262144  // h-hi slab elems (256*1024)

__device__ inline u16 f2bf(float f) {
  unsigned u = __float_as_uint(f);
  return (u16)((u + 0x7fffu + ((u >> 16) & 1u)) >> 16);
}
__device__ inline float bf2f(u16 h) { return __uint_as_float(((unsigned)h) << 16); }
__device__ inline float sigf(float x) { return 1.f / (1.f + __expf(-x)); }
__device__ inline float tanh_fast(float x) { return 1.f - 2.f / (__expf(2.f * x) + 1.f); }
// interleaved weight-row R -> original gate-major row (gate in bits 3-4)
__device__ inline int origR2(int R) { return ((R >> 3) & 3) * 1024 + (R >> 5) * 8 + (R & 7); }

__device__ inline void gload_lds16(const u16* g, u16* l) {
  __builtin_amdgcn_global_load_lds(
      (const __attribute__((address_space(1))) void*)g,
      (__attribute__((address_space(3))) void*)l, 16, 0, 0);
}

__device__ __forceinline__ void gbar() { __builtin_amdgcn_s_barrier(); }
__device__ __forceinline__ void sbar() { __builtin_amdgcn_sched_barrier(0); }

template <int N>
__device__ __forceinline__ void waitv() {
  if constexpr (N == 0) asm volatile("s_waitcnt vmcnt(0)" ::: "memory");
  else if constexpr (N == 8) asm volatile("s_waitcnt vmcnt(8)" ::: "memory");
  else if constexpr (N == 12) asm volatile("s_waitcnt vmcnt(12)" ::: "memory");
  else if constexpr (N == 16) asm volatile("s_waitcnt vmcnt(16)" ::: "memory");
}

// ============================================================================
// stepk: one LSTM step. gates = [h_hi|h_lo] @ Beff^T (bf16x3, 3 combos),
// fused cell epilogue. A (h) staged via LDS (16KB/iter); B (weights) loaded
// DIRECTLY global->VGPR from fragment-packed BF (coalesced 1KB/instr), 1-deep
// register double buffer (two named banks, no dynamic indexing).
// Grid 256 = 4 mb x 64 nb (XCD-sliced nb). Tile 64x64, 4 waves 2x2.
// VMEM queue per iter: 8 B-loads then [wait] then 4 A-stages -> steady
// wait vmcnt(12) = A(t+2):4 + B(t+1):8 newer than B(t).
// ============================================================================
template <int NT>  // NT = 16 K-iters of 64
__global__ __launch_bounds__(256) void stepk(
    const u16* __restrict__ Ahi, const u16* __restrict__ Alo,
    const u16* __restrict__ BF, const float* __restrict__ bias,
    float* __restrict__ cbuf, u16* __restrict__ hhi, u16* __restrict__ hlo) {
  __shared__ __attribute__((aligned(16))) u16 ts[4 * 8192];  // 64 KB

  const int bid = blockIdx.x, tid = threadIdx.x;
  const int x = bid & 7, i = bid >> 3;
  const int nb = x * 8 + (i & 7);   // XCD x owns nb slice [x*8, x*8+8)
  const int mb = i >> 3;            // 0..3

  const int lane = tid & 63, wid = tid >> 6;
  const int wrow = (wid >> 1) * 32;
  const int wn = wid & 1;           // n-half: fragment base f = wn*2
  const int lr = lane & 15, kq = lane >> 4;

  // A staging: 4 units/thread, rows 0..63 = Ahi, 64..127 = Alo, swizzled src.
  const int tid3 = tid >> 3;
  const int jp = (tid & 7) ^ (tid3 & 7);
  int uoff[4];
#pragma unroll
  for (int u = 0; u < 4; u++) {
    int r = u * 32 + tid3;
    uoff[u] = (mb * 64 + (r & 63)) * 1024 + jp * 8;
  }

  // B fragments: BF + nb*131072, frag (kt,p,f,kh) at ((((kt*2+p)*4+f)*2+kh)<<9
  const u16* Bb = BF + (size_t)nb * 131072 + lane * 8;

  f32x4 acc[2][2];
#pragma unroll
  for (int m = 0; m < 2; m++)
#pragma unroll
    for (int n = 0; n < 2; n++) acc[m][n] = (f32x4)0.f;

  bf16x8 B0[8], B1[8];

  auto LOADB = [&](bf16x8(&Br)[8], int kt) {
#pragma unroll
    for (int p = 0; p < 2; p++)
#pragma unroll
      for (int n = 0; n < 2; n++)
#pragma unroll
        for (int kh = 0; kh < 2; kh++)
          Br[p * 4 + n * 2 + kh] =
              *(const bf16x8*)(Bb + (((((kt * 2 + p) * 4) + wn * 2 + n) * 2 + kh) << 9));
  };

  auto STAGE = [&](int buf, int kt) {
    u16* lb = &ts[buf * 8192];
#pragma unroll
    for (int u = 0; u < 4; u++)
      gload_lds16((u < 2 ? Ahi : Alo) + uoff[u] + kt * 64, lb + (u * 256 + tid) * 8);
  };

  auto COMPUTE = [&](int cur, const bf16x8(&Br)[8]) {
    const char* base = (const char*)&ts[cur * 8192];
    const int sw0 = (lr & 7) * 16;
    bf16x8 ah[2][2], al[2][2];
#pragma unroll
    for (int m = 0; m < 2; m++)
#pragma unroll
      for (int kh = 0; kh < 2; kh++) {
        int row = wrow + m * 16 + lr;
        int so = ((kh * 4 + kq) * 16) ^ sw0;
        ah[m][kh] = *(const bf16x8*)(base + row * 128 + so);
        al[m][kh] = *(const bf16x8*)(base + (row + 64) * 128 + so);
      }
#pragma unroll
    for (int kh = 0; kh < 2; kh++)
#pragma unroll
      for (int m = 0; m < 2; m++)
#pragma unroll
        for (int n = 0; n < 2; n++) {
          acc[m][n] = __builtin_amdgcn_mfma_f32_16x16x32_bf16(ah[m][kh], Br[n * 2 + kh], acc[m][n], 0, 0, 0);
          acc[m][n] = __builtin_amdgcn_mfma_f32_16x16x32_bf16(al[m][kh], Br[n * 2 + kh], acc[m][n], 0, 0, 0);
          acc[m][n] = __builtin_amdgcn_mfma_f32_16x16x32_bf16(ah[m][kh], Br[4 + n * 2 + kh], acc[m][n], 0, 0, 0);
        }
  };

  auto BODY = [&](int t, const bf16x8(&Bc)[8], bf16x8(&Bn)[8]) {
    if (t + 1 < NT) LOADB(Bn, t + 1);
    if (t == NT - 1) waitv<0>();
    else if (t == NT - 2) waitv<8>();
    else waitv<12>();
    gbar();
    if (t + 3 < NT) STAGE((t + 3) & 3, t + 3);
    COMPUTE(t & 3, Bc);
  };

  // prologue: 4 ordered VMEM groups (sched_barrier keeps issue order = count model)
  LOADB(B0, 0); sbar();
  STAGE(0, 0); sbar();
  STAGE(1, 1); sbar();
  STAGE(2, 2); sbar();
#pragma unroll
  for (int tt = 0; tt < NT / 2; tt++) {
    BODY(2 * tt, B0, B1);
    BODY(2 * tt + 1, B1, B0);
  }

  // fused LSTM cell. Block tile: 64 batch rows x 64 interleaved R cols.
  // R = nb*64 + rr: gate = (rr>>3)&3, n = nb*16 + (rr>>5)*8 + (rr&7).
  float* g = (float*)ts;  // 64 x 65 f32 exchange (16.6 KB, fits)
  __syncthreads();
#pragma unroll
  for (int m = 0; m < 2; m++)
#pragma unroll
    for (int n = 0; n < 2; n++)
#pragma unroll
      for (int j = 0; j < 4; j++)
        g[(wrow + m * 16 + kq * 4 + j) * 65 + wn * 32 + n * 16 + lr] = acc[m][n][j];
  __syncthreads();
  const int n16 = tid & 15;
  const int s = n16 & 7, q = n16 >> 3;
  const int cbase = q * 32 + s;
  const float bi = bias[nb * 64 + cbase];
  const float bf = bias[nb * 64 + cbase + 8];
  const float bg = bias[nb * 64 + cbase + 16];
  const float bo = bias[nb * 64 + cbase + 24];
#pragma unroll
  for (int i2 = 0; i2 < 4; i2++) {
    int br = (tid >> 4) + i2 * 16;
    float xi = g[br * 65 + cbase] + bi;
    float xf = g[br * 65 + cbase + 8] + bf;
    float xg = g[br * 65 + cbase + 16] + bg;
    float xo = g[br * 65 + cbase + 24] + bo;
    int b = mb * 64 + br;
    int col = nb * 16 + n16;
    int cidx = b * 1024 + col;
    float cn = sigf(xf) * cbuf[cidx] + sigf(xi) * tanh_fast(xg);
    float h = sigf(xo) * tanh_fast(cn);
    cbuf[cidx] = cn;
    u16 hi = f2bf(h);
    u16 lo = f2bf(h - bf2f(hi));
    hhi[cidx] = hi;
    hlo[cidx] = lo;
  }
}

// ============================================================================
// gemmk: general LDS-staged GEMM (used for W_c prep, step 0, y-GEMM).
// Unchanged (proven R5).
// ============================================================================
template <int BM, int BN, int NT, int MODE, int EPI, int SWZ, int NBW>
__global__ __launch_bounds__(256) void gemmk(
    const u16* __restrict__ A0p, const u16* __restrict__ A1p,
    const u16* __restrict__ A2p, const u16* __restrict__ A3p,
    const u16* __restrict__ B0p, const u16* __restrict__ B1p,
    const u16* __restrict__ B2p, const u16* __restrict__ B3p,
    const float* __restrict__ bias, float* __restrict__ cbuf,
    u16* __restrict__ hhi, u16* __restrict__ hlo, float* __restrict__ fout) {
  constexpr int TSE = 256 * 64;
  constexpr int MR = BM / 32;
  constexpr int NR = BN / 32;

  __shared__ __attribute__((aligned(16))) u16 ts[4 * TSE];

  const int bid = blockIdx.x, tid = threadIdx.x;
  int mb, nb;
  if constexpr (SWZ == 1) {
    int x = bid & 7, i = bid >> 3;
    nb = x * 8 + (i & 7);
    mb = i >> 3;
  } else if constexpr (SWZ == 2) {
    int x = bid & 7, i = bid >> 3;
    nb = i & 7;
    mb = x * 32 + (i >> 3);
  } else {
    nb = bid % NBW;
    mb = bid / NBW;
  }

  const int lane = tid & 63, wid = tid >> 6;
  const int wrow = (wid >> 1) * (BM / 2);
  const int wcol = (wid & 1) * (BN / 2);
  const int lr = lane & 15, kq = lane >> 4;

  const size_t Aoff = (size_t)mb * BM * 1024;
  const size_t Boff = (size_t)nb * BN * 1024;
  const int tid3 = tid >> 3;
  const int jp = (tid & 7) ^ (tid3 & 7);

  f32x4 acc[MR][NR];
#pragma unroll
  for (int m = 0; m < MR; m++)
#pragma unroll
    for (int n = 0; n < NR; n++) acc[m][n] = (f32x4)0.f;

  auto STAGE = [&](int buf, int kt) {
    const u16 *a0, *a1, *b0, *b1;
    int ko;
    if constexpr (MODE == 1) {
      if (kt >= NT / 2) { a0 = A2p; a1 = A3p; b0 = B2p; b1 = B3p; ko = (kt - NT / 2) * 64; }
      else { a0 = A0p; a1 = A1p; b0 = B0p; b1 = B1p; ko = kt * 64; }
    } else {
      a0 = A0p; a1 = A1p; b0 = B0p; b1 = B1p; ko = kt * 64;
    }
    u16* lb = &ts[buf * TSE];
#pragma unroll
    for (int u = 0; u < 8; u++) {
      const u16* src;
      int prow;
      if constexpr (MODE == 2) {
        if (u < BM / 32) { src = a0 + Aoff; prow = u * 32 + tid3; }
        else { src = b0 + Boff; prow = (u - BM / 32) * 32 + tid3; }
      } else {
        int s = u >> 1;
        src = (s == 0 ? a0 + Aoff : s == 1 ? a1 + Aoff : s == 2 ? b0 + Boff : b1 + Boff);
        prow = (u & 1) * 32 + tid3;
      }
      gload_lds16(src + prow * 1024 + jp * 8 + ko, lb + (u * 256 + tid) * 8);
    }
  };

  auto COMPUTE = [&](int cur) {
    const char* base = (const char*)&ts[cur * TSE];
    int sw0 = (lr & 7) * 16;
    if constexpr (MODE == 2) {
      bf16x8 a[MR][2], b[NR][2];
#pragma unroll
      for (int m = 0; m < MR; m++)
#pragma unroll
        for (int kh = 0; kh < 2; kh++) {
          int row = wrow + m * 16 + lr;
          a[m][kh] = *(const bf16x8*)(base + row * 128 + (((kh * 4 + kq) * 16) ^ sw0));
        }
#pragma unroll
      for (int n = 0; n < NR; n++)
#pragma unroll
        for (int kh = 0; kh < 2; kh++) {
          int row = BM + wcol + n * 16 + lr;
          b[n][kh] = *(const bf16x8*)(base + row * 128 + (((kh * 4 + kq) * 16) ^ sw0));
        }
#pragma unroll
      for (int kh = 0; kh < 2; kh++)
#pragma unroll
        for (int m = 0; m < MR; m++)
#pragma unroll
          for (int n = 0; n < NR; n++)
            acc[m][n] = __builtin_amdgcn_mfma_f32_16x16x32_bf16(a[m][kh], b[n][kh], acc[m][n], 0, 0, 0);
    } else {
      bf16x8 ah[2][2], al[2][2], bh[2][2], bl[2][2];
#pragma unroll
      for (int m = 0; m < 2; m++)
#pragma unroll
        for (int kh = 0; kh < 2; kh++) {
          int row = wrow + m * 16 + lr;
          int so = ((kh * 4 + kq) * 16) ^ sw0;
          ah[m][kh] = *(const bf16x8*)(base + row * 128 + so);
          al[m][kh] = *(const bf16x8*)(base + (row + 64) * 128 + so);
        }
#pragma unroll
      for (int n = 0; n < 2; n++)
#pragma unroll
        for (int kh = 0; kh < 2; kh++) {
          int row = 128 + wcol + n * 16 + lr;
          int so = ((kh * 4 + kq) * 16) ^ sw0;
          bh[n][kh] = *(const bf16x8*)(base + row * 128 + so);
          bl[n][kh] = *(const bf16x8*)(base + (row + 64) * 128 + so);
        }
#pragma unroll
      for (int kh = 0; kh < 2; kh++)
#pragma unroll
        for (int m = 0; m < 2; m++)
#pragma unroll
          for (int n = 0; n < 2; n++) {
            acc[m][n] = __builtin_amdgcn_mfma_f32_16x16x32_bf16(ah[m][kh], bh[n][kh], acc[m][n], 0, 0, 0);
            acc[m][n] = __builtin_amdgcn_mfma_f32_16x16x32_bf16(al[m][kh], bh[n][kh], acc[m][n], 0, 0, 0);
            acc[m][n] = __builtin_amdgcn_mfma_f32_16x16x32_bf16(ah[m][kh], bl[n][kh], acc[m][n], 0, 0, 0);
          }
    }
  };

  STAGE(0, 0);
  STAGE(1, 1);
  STAGE(2, 2);
  for (int t = 0; t < NT - 3; t++) {
    waitv<16>();
    gbar();
    STAGE((t + 3) & 3, t + 3);
    COMPUTE(t & 3);
  }
  waitv<16>(); gbar(); COMPUTE((NT - 3) & 3);
  waitv<8>();  gbar(); COMPUTE((NT - 2) & 3);
  waitv<0>();  gbar(); COMPUTE((NT - 1) & 3);

  if constexpr (EPI == 0 || EPI == 2) {
    float* Cb = fout + (size_t)(mb * BM + wrow) * 1024 + nb * BN + wcol;
#pragma unroll
    for (int n = 0; n < NR; n++) {
      float blv = (EPI == 2) ? bias[nb * BN + wcol + n * 16 + lr] : 0.f;
#pragma unroll
      for (int m = 0; m < MR; m++)
#pragma unroll
        for (int j = 0; j < 4; j++)
          Cb[(size_t)(m * 16 + kq * 4 + j) * 1024 + n * 16 + lr] = acc[m][n][j] + blv;
    }
  } else {
    float* g = (float*)ts;
    __syncthreads();
#pragma unroll
    for (int m = 0; m < 2; m++)
#pragma unroll
      for (int n = 0; n < 2; n++)
#pragma unroll
        for (int j = 0; j < 4; j++)
          g[(wrow + m * 16 + kq * 4 + j) * 65 + wcol + n * 16 + lr] = acc[m][n][j];
    __syncthreads();
    const int n16 = tid & 15;
    const int s = n16 & 7, q = n16 >> 3;
    const int cbase = q * 32 + s;
    const float bi = bias[nb * 64 + cbase];
    const float bf = bias[nb * 64 + cbase + 8];
    const float bg = bias[nb * 64 + cbase + 16];
    const float bo = bias[nb * 64 + cbase + 24];
#pragma unroll
    for (int i2 = 0; i2 < 4; i2++) {
      int br = (tid >> 4) + i2 * 16;
      float xi = g[br * 65 + cbase] + bi;
      float xf = g[br * 65 + cbase + 8] + bf;
      float xg = g[br * 65 + cbase + 16] + bg;
      float xo = g[br * 65 + cbase + 24] + bo;
      int b = mb * 64 + br;
      int col = nb * 16 + n16;
      int cidx = b * 1024 + col;
      float cn = sigf(xf) * cbuf[cidx] + sigf(xi) * tanh_fast(xg);
      float h = sigf(xo) * tanh_fast(cn);
      cbuf[cidx] = cn;
      u16 hi = f2bf(h);
      u16 lo = f2bf(h - bf2f(hi));
      hhi[cidx] = hi;
      hlo[cidx] = lo;
    }
  }
}

// ---- prep kernels ----

template <bool IMAP, bool WLO>
__global__ __launch_bounds__(256) void prep_split(const float* __restrict__ src,
                                                  u16* __restrict__ hi_p,
                                                  u16* __restrict__ lo_p) {
  int i = blockIdx.x * 256 + threadIdx.x;
  int r = i >> 7, k8 = (i & 127) << 3;
  int orig = IMAP ? origR2(r) : r;
  const float* s = src + (size_t)orig * 1024 + k8;
  u16x8 oh, ol;
#pragma unroll
  for (int e = 0; e < 8; e++) {
    float f = s[e];
    u16 h = f2bf(f);
    oh[e] = h;
    if constexpr (WLO) ol[e] = f2bf(f - bf2f(h));
  }
  *(u16x8*)&hi_p[(size_t)r * 1024 + k8] = oh;
  if constexpr (WLO) *(u16x8*)&lo_p[(size_t)r * 1024 + k8] = ol;
}

__global__ __launch_bounds__(256) void prep_wlt(const float* __restrict__ W,
                                                u16* __restrict__ hi_p,
                                                u16* __restrict__ lo_p) {
  int i = blockIdx.x * 256 + threadIdx.x;
  int k = i >> 7, j8 = (i & 127) << 3;
  u16x8 oh, ol;
#pragma unroll
  for (int e = 0; e < 8; e++) {
    float f = W[(size_t)(j8 + e) * 1024 + k];
    u16 h = f2bf(f);
    oh[e] = h;
    ol[e] = f2bf(f - bf2f(h));
  }
  *(u16x8*)&hi_p[(size_t)k * 1024 + j8] = oh;
  *(u16x8*)&lo_p[(size_t)k * 1024 + j8] = ol;
}

// Beff fragment-packed: BF[nb][kt][p][f][kh][lane][8e]; value = Wc[R]+Whh[origR2(R)]
// Exactly 64nb x 131072 elems = 8,388,608 elems -> 4096 blocks x 256 thr x 8e.
__global__ __launch_bounds__(256) void prep_beff2(const float* __restrict__ Wc,
                                                  const float* __restrict__ Whh,
                                                  u16* __restrict__ BF) {
  int i8 = blockIdx.x * 256 + threadIdx.x;  // 1,048,576 threads x 8 elems
  int o = i8 * 8;
  int l = (o >> 3) & 63;
  int kh = (o >> 9) & 1;
  int f = (o >> 10) & 3;
  int p = (o >> 12) & 1;
  int kt = (o >> 13) & 15;
  int nb = o >> 17;
  if (nb >= 64) return;  // defensive (grid sized exactly; keep guard anyway)
  int R = nb * 64 + f * 16 + (l & 15);
  int k = kt * 64 + kh * 32 + (l >> 4) * 8;
  const float* s1 = Wc + (size_t)R * 1024 + k;
  const float* s2 = Whh + (size_t)origR2(R) * 1024 + k;
  u16x8 out;
#pragma unroll
  for (int e = 0; e < 8; e++) {
    float v = s1[e] + s2[e];
    u16 h = f2bf(v);
    out[e] = p ? f2bf(v - bf2f(h)) : h;
  }
  *(u16x8*)&BF[o] = out;
}

__global__ __launch_bounds__(256) void prep_a0(const float* __restrict__ x0,
                                               const float* __restrict__ h0,
                                               const float* __restrict__ c0,
                                               u16* __restrict__ xhi, u16* __restrict__ xlo,
                                               u16* __restrict__ hhi, u16* __restrict__ hlo,
                                               float* __restrict__ cbuf) {
  int i = blockIdx.x * 256 + threadIdx.x;
  int sel = i >> 15, ii = i & 32767;
  int r = ii >> 7, k8 = (ii & 127) << 3;
  const float* s = (sel ? h0 : x0) + r * 1024 + k8;
  u16* hp = (sel ? hhi : xhi) + r * 1024 + k8;
  u16* lp = (sel ? hlo : xlo) + r * 1024 + k8;
  u16x8 oh, ol;
#pragma unroll
  for (int e = 0; e < 8; e++) {
    float f = s[e];
    u16 h = f2bf(f);
    oh[e] = h;
    ol[e] = f2bf(f - bf2f(h));
  }
  *(u16x8*)hp = oh;
  *(u16x8*)lp = ol;
  if (i < 32768) {
    float4 v0 = *(const float4*)&c0[i * 8];
    float4 v1 = *(const float4*)&c0[i * 8 + 4];
    *(float4*)&cbuf[i * 8] = v0;
    *(float4*)&cbuf[i * 8 + 4] = v1;
  }
}

__global__ __launch_bounds__(256) void prep_bias(const float* __restrict__ Wih,
                                                 const float* __restrict__ b_ih,
                                                 const float* __restrict__ b_hh,
                                                 const float* __restrict__ b_lin,
                                                 float* __restrict__ bc0,
                                                 float* __restrict__ bc1) {
  int wid = threadIdx.x >> 6, lane = threadIdx.x & 63;
  int R = blockIdx.x * 4 + wid;
  int o = origR2(R);
  float p = 0.f;
#pragma unroll
  for (int it = 0; it < 16; it++) p += Wih[(size_t)o * 1024 + lane + it * 64] * b_lin[lane + it * 64];
#pragma unroll
  for (int m = 1; m < 64; m <<= 1) p += __shfl_xor(p, m);
  if (lane == 0) {
    float s = b_ih[o] + b_hh[o];
    bc0[R] = s;
    bc1[R] = s + p;
  }
}

__global__ __launch_bounds__(256) void bn_kernel(float* __restrict__ out) {
  int t = blockIdx.x >> 2;
  int d = ((blockIdx.x & 3) << 8) + threadIdx.x;
  float* base = out + (size_t)t * (256 * 1024) + d;
  float s = 0.f, s2 = 0.f;
  for (int b = 0; b < 256; b++) {
    float v = base[b * 1024];
    s += v;
    s2 += v * v;
  }
  float mean = s * (1.f / 256.f);
  float var = fmaxf(s2 * (1.f / 256.f) - mean * mean, 0.f);
  float rstd = rsqrtf(var + 1e-5f);
  for (int b = 0; b < 256; b++) base[b * 1024] = (base[b * 1024] - mean) * rstd;
}

extern "C" void kernel_launch(void* const* d_in, const int* in_sizes, int n_in,
                              void* d_out, int out_size, void* d_ws, size_t ws_size,
                              hipStream_t stream) {
  const float* inputs = (const float*)d_in[0];
  const float* W_ih = (const float*)d_in[1];
  const float* W_hh = (const float*)d_in[2];
  const float* b_ih = (const float*)d_in[3];
  const float* b_hh = (const float*)d_in[4];
  const float* W_lin = (const float*)d_in[5];
  const float* b_lin = (const float*)d_in[6];
  const float* h0 = (const float*)d_in[7];
  const float* c0 = (const float*)d_in[8];
  float* out = (float*)d_out;

  char* ws = (char*)d_ws;
  float* bc0 = (float*)(ws + 0);             // 16,384
  float* bc1 = (float*)(ws + 16384);         // 16,384
  float* cbuf = (float*)(ws + 32768);        // 1,048,576
  u16* Wlin_hi = (u16*)(ws + 1081344);       // 2,097,152
  u16* BF = (u16*)(ws + 3178496);            // 16,777,216 (fragment-packed Beff)
  u16* xhi = (u16*)(ws + 19955712);          // 524,288
  u16* xlo = (u16*)(ws + 20480000);          // 524,288
  u16* h0hi = (u16*)(ws + 21004288);         // 524,288
  u16* h0lo = (u16*)(ws + 21528576);         // 524,288
  u16* Hlo0 = (u16*)(ws + 22052864);         // 524,288
  u16* Hlo1 = (u16*)(ws + 22577152);         // 524,288
  u16* Hhi = (u16*)(ws + 23101440);          // 67,108,864 (128 slabs of 512KB)
  // transients aliased inside Hhi (dead after prep / step 0; first alias = slab 4,
  // first overwritten by step kernel t=4 which runs strictly later):
  u16* Whh_hi = (u16*)(ws + 23101440 + 2097152);    // slabs 4..19
  u16* Whh_lo = (u16*)(ws + 23101440 + 10485760);   // slabs 20..35
  u16* Wih_hi = (u16*)(ws + 23101440 + 18874368);   // slabs 36..51
  u16* Wih_lo = (u16*)(ws + 23101440 + 27262976);   // slabs 52..67
  u16* Wlt_hi = (u16*)(ws + 23101440 + 35651584);   // slabs 68..71
  u16* Wlt_lo = (u16*)(ws + 23101440 + 37748736);   // slabs 72..75
  float* Wc_f32 = (float*)(ws + 23101440 + 39845888);  // slabs 76..107

  prep_split<true, true><<<2048, 256, 0, stream>>>(W_ih, Wih_hi, Wih_lo);
  prep_split<true, true><<<2048, 256, 0, stream>>>(W_hh, Whh_hi, Whh_lo);
  prep_split<false, false><<<512, 256, 0, stream>>>(W_lin, Wlin_hi, nullptr);
  prep_wlt<<<512, 256, 0, stream>>>(W_lin, Wlt_hi, Wlt_lo);
  prep_a0<<<256, 256, 0, stream>>>(inputs, h0, c0, xhi, xlo, h0hi, h0lo, cbuf);
  prep_bias<<<1024, 256, 0, stream>>>(W_ih, b_ih, b_hh, b_lin, bc0, bc1);

  // W_c = W_ih @ W_lin (bf16x3), rows interleaved. M=4096, N=1024, K=1024.
  gemmk<64, 64, 16, 0, 0, 0, 16><<<1024, 256, 0, stream>>>(
      Wih_hi, Wih_lo, nullptr, nullptr, Wlt_hi, Wlt_lo, nullptr, nullptr,
      nullptr, nullptr, nullptr, nullptr, Wc_f32);
  prep_beff2<<<4096, 256, 0, stream>>>(Wc_f32, W_hh, BF);

  // step 0: gates from (x0,h0): two K-phases (x @ Wih, h @ Whh), K=2048 total.
  gemmk<64, 64, 32, 1, 1, 1, 0><<<256, 256, 0, stream>>>(
      xhi, xlo, h0hi, h0lo, Wih_hi, Wih_lo, Whh_hi, Whh_lo,
      bc0, cbuf, Hhi, Hlo0, nullptr);
  // steps 1..127: B-direct stepk, K=1024 (bf16x3).
  for (int t = 1; t < 128; t++) {
    stepk<16><<<256, 256, 0, stream>>>(
        Hhi + (size_t)(t - 1) * SLABH, ((t - 1) & 1) ? Hlo1 : Hlo0,
        BF, bc1, cbuf, Hhi + (size_t)t * SLABH, (t & 1) ? Hlo1 : Hlo0);
  }

  // ys = Hs_hi @ W_lin_hi^T + b_lin (plain bf16). M=32768, N=1024, K=1024.
  gemmk<128, 128, 16, 2, 2, 2, 0><<<2048, 256, 0, stream>>>(
      Hhi, nullptr, nullptr, nullptr, Wlin_hi, nullptr, nullptr, nullptr,
      b_lin, nullptr, nullptr, nullptr, out);
  bn_kernel<<<512, 256, 0, stream>>>(out);
}

// Round 8
// 1563.418 us; speedup vs baseline: 1.1310x; 1.1310x over previous
//
#include <hip/hip_runtime.h>

typedef unsigned short u16;
typedef short bf16x8 __attribute__((ext_vector_type(8)));
typedef float f32x4 __attribute__((ext_vector_type(4)));
typedef u16 u16x8 __attribute__((ext_vector_type(8)));

#define SLABH 262144  // h-hi slab elems (256*1024)

__device__ inline u16 f2bf(float f) {
  unsigned u = __float_as_uint(f);
  return (u16)((u + 0x7fffu + ((u >> 16) & 1u)) >> 16);
}
__device__ inline float bf2f(u16 h) { return __uint_as_float(((unsigned)h) << 16); }
__device__ inline float sigf(float x) { return 1.f / (1.f + __expf(-x)); }
__device__ inline float tanh_fast(float x) { return 1.f - 2.f / (__expf(2.f * x) + 1.f); }
// interleaved weight-row R -> original gate-major row (gate in bits 3-4)
__device__ inline int origR2(int R) { return ((R >> 3) & 3) * 1024 + (R >> 5) * 8 + (R & 7); }

__device__ inline void gload_lds16(const u16* g, u16* l) {
  __builtin_amdgcn_global_load_lds(
      (const __attribute__((address_space(1))) void*)g,
      (__attribute__((address_space(3))) void*)l, 16, 0, 0);
}

__device__ __forceinline__ void gbar() { __builtin_amdgcn_s_barrier(); }

template <int N>
__device__ __forceinline__ void waitv() {
  if constexpr (N == 0) asm volatile("s_waitcnt vmcnt(0)" ::: "memory");
  else if constexpr (N == 8) asm volatile("s_waitcnt vmcnt(8)" ::: "memory");
  else if constexpr (N == 16) asm volatile("s_waitcnt vmcnt(16)" ::: "memory");
}

// ============================================================================
// gemmk: LDS-staged GEMM. C[m][n] = sum_k A[m][k]*B[n][k], planes pitch 1024.
// MODE 0: bf16x3 joint staging (Ahi|Alo|Bhi|Blo rows), 3 combos.
// MODE 1: like 0, two K-phases with different plane sets (step 0).
// MODE 2: plain bf16 hi-only.
// 256 LDS rows x 64 k per buf (32 KB), 4 bufs, depth-3 prefetch,
// XOR-swizzle on global source + ds_read.
// EPI: 0 = f32 store; 1 = fused LSTM cell (BM=BN=64); 2 = f32 + bias store;
//      3 = f32 store + per-column batch-stat atomics (BM=128: rows = one t).
// SWZ: 0 = nb-major; 1 = step map; 2 = y mb-slice map; 3 = y 8x8-square map.
// ============================================================================
template <int BM, int BN, int NT, int MODE, int EPI, int SWZ, int NBW>
__global__ __launch_bounds__(256) void gemmk(
    const u16* __restrict__ A0p, const u16* __restrict__ A1p,
    const u16* __restrict__ A2p, const u16* __restrict__ A3p,
    const u16* __restrict__ B0p, const u16* __restrict__ B1p,
    const u16* __restrict__ B2p, const u16* __restrict__ B3p,
    const float* __restrict__ bias, float* __restrict__ cbuf,
    u16* __restrict__ hhi, u16* __restrict__ hlo, float* __restrict__ fout) {
  constexpr int TSE = 256 * 64;
  constexpr int MR = BM / 32;
  constexpr int NR = BN / 32;

  __shared__ __attribute__((aligned(16))) u16 ts[4 * TSE];

  const int bid = blockIdx.x, tid = threadIdx.x;
  int mb, nb;
  if constexpr (SWZ == 1) {        // steps: XCD owns 8-wide nb slice, all mb
    int x = bid & 7, i = bid >> 3;
    nb = x * 8 + (i & 7);
    mb = i >> 3;
  } else if constexpr (SWZ == 2) { // y: XCD owns 32-wide mb slice
    int x = bid & 7, i = bid >> 3;
    nb = i & 7;
    mb = x * 32 + (i >> 3);
  } else if constexpr (SWZ == 3) { // y: XCD owns 8mb x 8nb squares (L2-fit)
    int x = bid & 7, i = bid >> 3;
    int g = i >> 6, r = i & 63;
    mb = x * 8 + g * 64 + (r >> 3);
    nb = r & 7;
  } else {
    nb = bid % NBW;
    mb = bid / NBW;
  }

  const int lane = tid & 63, wid = tid >> 6;
  const int wrow = (wid >> 1) * (BM / 2);
  const int wcol = (wid & 1) * (BN / 2);
  const int lr = lane & 15, kq = lane >> 4;

  const size_t Aoff = (size_t)mb * BM * 1024;
  const size_t Boff = (size_t)nb * BN * 1024;
  const int tid3 = tid >> 3;
  const int jp = (tid & 7) ^ (tid3 & 7);

  f32x4 acc[MR][NR];
#pragma unroll
  for (int m = 0; m < MR; m++)
#pragma unroll
    for (int n = 0; n < NR; n++) acc[m][n] = (f32x4)0.f;

  auto STAGE = [&](int buf, int kt) {
    const u16 *a0, *a1, *b0, *b1;
    int ko;
    if constexpr (MODE == 1) {
      if (kt >= NT / 2) { a0 = A2p; a1 = A3p; b0 = B2p; b1 = B3p; ko = (kt - NT / 2) * 64; }
      else { a0 = A0p; a1 = A1p; b0 = B0p; b1 = B1p; ko = kt * 64; }
    } else {
      a0 = A0p; a1 = A1p; b0 = B0p; b1 = B1p; ko = kt * 64;
    }
    u16* lb = &ts[buf * TSE];
#pragma unroll
    for (int u = 0; u < 8; u++) {
      const u16* src;
      int prow;
      if constexpr (MODE == 2) {
        if (u < BM / 32) { src = a0 + Aoff; prow = u * 32 + tid3; }
        else { src = b0 + Boff; prow = (u - BM / 32) * 32 + tid3; }
      } else {
        int s = u >> 1;
        src = (s == 0 ? a0 + Aoff : s == 1 ? a1 + Aoff : s == 2 ? b0 + Boff : b1 + Boff);
        prow = (u & 1) * 32 + tid3;
      }
      gload_lds16(src + prow * 1024 + jp * 8 + ko, lb + (u * 256 + tid) * 8);
    }
  };

  auto COMPUTE = [&](int cur) {
    const char* base = (const char*)&ts[cur * TSE];
    int sw0 = (lr & 7) * 16;
    if constexpr (MODE == 2) {
      bf16x8 a[MR][2], b[NR][2];
#pragma unroll
      for (int m = 0; m < MR; m++)
#pragma unroll
        for (int kh = 0; kh < 2; kh++) {
          int row = wrow + m * 16 + lr;
          a[m][kh] = *(const bf16x8*)(base + row * 128 + (((kh * 4 + kq) * 16) ^ sw0));
        }
#pragma unroll
      for (int n = 0; n < NR; n++)
#pragma unroll
        for (int kh = 0; kh < 2; kh++) {
          int row = BM + wcol + n * 16 + lr;
          b[n][kh] = *(const bf16x8*)(base + row * 128 + (((kh * 4 + kq) * 16) ^ sw0));
        }
#pragma unroll
      for (int kh = 0; kh < 2; kh++)
#pragma unroll
        for (int m = 0; m < MR; m++)
#pragma unroll
          for (int n = 0; n < NR; n++)
            acc[m][n] = __builtin_amdgcn_mfma_f32_16x16x32_bf16(a[m][kh], b[n][kh], acc[m][n], 0, 0, 0);
    } else {
      bf16x8 ah[2][2], al[2][2], bh[2][2], bl[2][2];
#pragma unroll
      for (int m = 0; m < 2; m++)
#pragma unroll
        for (int kh = 0; kh < 2; kh++) {
          int row = wrow + m * 16 + lr;
          int so = ((kh * 4 + kq) * 16) ^ sw0;
          ah[m][kh] = *(const bf16x8*)(base + row * 128 + so);
          al[m][kh] = *(const bf16x8*)(base + (row + 64) * 128 + so);
        }
#pragma unroll
      for (int n = 0; n < 2; n++)
#pragma unroll
        for (int kh = 0; kh < 2; kh++) {
          int row = 128 + wcol + n * 16 + lr;
          int so = ((kh * 4 + kq) * 16) ^ sw0;
          bh[n][kh] = *(const bf16x8*)(base + row * 128 + so);
          bl[n][kh] = *(const bf16x8*)(base + (row + 64) * 128 + so);
        }
#pragma unroll
      for (int kh = 0; kh < 2; kh++)
#pragma unroll
        for (int m = 0; m < 2; m++)
#pragma unroll
          for (int n = 0; n < 2; n++) {
            acc[m][n] = __builtin_amdgcn_mfma_f32_16x16x32_bf16(ah[m][kh], bh[n][kh], acc[m][n], 0, 0, 0);
            acc[m][n] = __builtin_amdgcn_mfma_f32_16x16x32_bf16(al[m][kh], bh[n][kh], acc[m][n], 0, 0, 0);
            acc[m][n] = __builtin_amdgcn_mfma_f32_16x16x32_bf16(ah[m][kh], bl[n][kh], acc[m][n], 0, 0, 0);
          }
    }
  };

  STAGE(0, 0);
  STAGE(1, 1);
  STAGE(2, 2);
  for (int t = 0; t < NT - 3; t++) {
    waitv<16>();
    gbar();
    STAGE((t + 3) & 3, t + 3);
    COMPUTE(t & 3);
  }
  waitv<16>(); gbar(); COMPUTE((NT - 3) & 3);
  waitv<8>();  gbar(); COMPUTE((NT - 2) & 3);
  waitv<0>();  gbar(); COMPUTE((NT - 1) & 3);

  if constexpr (EPI == 0 || EPI == 2) {
    float* Cb = fout + (size_t)(mb * BM + wrow) * 1024 + nb * BN + wcol;
#pragma unroll
    for (int n = 0; n < NR; n++) {
      float blv = (EPI == 2) ? bias[nb * BN + wcol + n * 16 + lr] : 0.f;
#pragma unroll
      for (int m = 0; m < MR; m++)
#pragma unroll
        for (int j = 0; j < 4; j++)
          Cb[(size_t)(m * 16 + kq * 4 + j) * 1024 + n * 16 + lr] = acc[m][n][j] + blv;
    }
  } else if constexpr (EPI == 3) {
    // f32 store + column batch-stats. BM=128 => block rows all in t = mb>>1.
    // cbuf = stats base: S at [t*1024+col], S2 at +131072.
    float* Cb = fout + (size_t)(mb * BM + wrow) * 1024 + nb * BN + wcol;
    const int t = mb >> 1;
#pragma unroll
    for (int n = 0; n < NR; n++) {
      float s = 0.f, s2 = 0.f;
#pragma unroll
      for (int m = 0; m < MR; m++)
#pragma unroll
        for (int j = 0; j < 4; j++) {
          float v = acc[m][n][j];
          Cb[(size_t)(m * 16 + kq * 4 + j) * 1024 + n * 16 + lr] = v;
          s += v;
          s2 += v * v;
        }
      // reduce across kq lanes (bits 4-5): column totals over this wave's rows
      s += __shfl_xor(s, 16);  s += __shfl_xor(s, 32);
      s2 += __shfl_xor(s2, 16); s2 += __shfl_xor(s2, 32);
      if (kq == 0) {
        int col = nb * BN + wcol + n * 16 + lr;
        atomicAdd(&cbuf[t * 1024 + col], s);
        atomicAdd(&cbuf[131072 + t * 1024 + col], s2);
      }
    }
  } else {
    // fused LSTM cell (BM=BN=64). R = nb*64+rr: gate=(rr>>3)&3, n=nb*16+(rr>>5)*8+(rr&7)
    float* g = (float*)ts;
    __syncthreads();
#pragma unroll
    for (int m = 0; m < 2; m++)
#pragma unroll
      for (int n = 0; n < 2; n++)
#pragma unroll
        for (int j = 0; j < 4; j++)
          g[(wrow + m * 16 + kq * 4 + j) * 65 + wcol + n * 16 + lr] = acc[m][n][j];
    __syncthreads();
    const int n16 = tid & 15;
    const int s = n16 & 7, q = n16 >> 3;
    const int cbase = q * 32 + s;
    const float bi = bias[nb * 64 + cbase];
    const float bf = bias[nb * 64 + cbase + 8];
    const float bg = bias[nb * 64 + cbase + 16];
    const float bo = bias[nb * 64 + cbase + 24];
#pragma unroll
    for (int i2 = 0; i2 < 4; i2++) {
      int br = (tid >> 4) + i2 * 16;
      float xi = g[br * 65 + cbase] + bi;
      float xf = g[br * 65 + cbase + 8] + bf;
      float xg = g[br * 65 + cbase + 16] + bg;
      float xo = g[br * 65 + cbase + 24] + bo;
      int b = mb * 64 + br;
      int col = nb * 16 + n16;
      int cidx = b * 1024 + col;
      float cn = sigf(xf) * cbuf[cidx] + sigf(xi) * tanh_fast(xg);
      float h = sigf(xo) * tanh_fast(cn);
      cbuf[cidx] = cn;
      u16 hi = f2bf(h);
      u16 lo = f2bf(h - bf2f(hi));
      hhi[cidx] = hi;
      hlo[cidx] = lo;
    }
  }
}

// ---- prep kernels (planes pitch 1024) ----

template <bool IMAP, bool WLO>
__global__ __launch_bounds__(256) void prep_split(const float* __restrict__ src,
                                                  u16* __restrict__ hi_p,
                                                  u16* __restrict__ lo_p) {
  int i = blockIdx.x * 256 + threadIdx.x;
  int r = i >> 7, k8 = (i & 127) << 3;
  int orig = IMAP ? origR2(r) : r;
  const float* s = src + (size_t)orig * 1024 + k8;
  u16x8 oh, ol;
#pragma unroll
  for (int e = 0; e < 8; e++) {
    float f = s[e];
    u16 h = f2bf(f);
    oh[e] = h;
    if constexpr (WLO) ol[e] = f2bf(f - bf2f(h));
  }
  *(u16x8*)&hi_p[(size_t)r * 1024 + k8] = oh;
  if constexpr (WLO) *(u16x8*)&lo_p[(size_t)r * 1024 + k8] = ol;
}

__global__ __launch_bounds__(256) void prep_wlt(const float* __restrict__ W,
                                                u16* __restrict__ hi_p,
                                                u16* __restrict__ lo_p) {
  int i = blockIdx.x * 256 + threadIdx.x;
  int k = i >> 7, j8 = (i & 127) << 3;
  u16x8 oh, ol;
#pragma unroll
  for (int e = 0; e < 8; e++) {
    float f = W[(size_t)(j8 + e) * 1024 + k];
    u16 h = f2bf(f);
    oh[e] = h;
    ol[e] = f2bf(f - bf2f(h));
  }
  *(u16x8*)&hi_p[(size_t)k * 1024 + j8] = oh;
  *(u16x8*)&lo_p[(size_t)k * 1024 + j8] = ol;
}

// Beff[R] = split(Wc_f32[R] + W_hh[origR2(R)]) into hi/lo planes
__global__ __launch_bounds__(256) void prep_beff(const float* __restrict__ Wc,
                                                 const float* __restrict__ Whh,
                                                 u16* __restrict__ hi_p,
                                                 u16* __restrict__ lo_p) {
  int i = blockIdx.x * 256 + threadIdx.x;
  int r = i >> 7, k8 = (i & 127) << 3;
  const float* s1 = Wc + (size_t)r * 1024 + k8;
  const float* s2 = Whh + (size_t)origR2(r) * 1024 + k8;
  u16x8 oh, ol;
#pragma unroll
  for (int e = 0; e < 8; e++) {
    float f = s1[e] + s2[e];
    u16 h = f2bf(f);
    oh[e] = h;
    ol[e] = f2bf(f - bf2f(h));
  }
  *(u16x8*)&hi_p[(size_t)r * 1024 + k8] = oh;
  *(u16x8*)&lo_p[(size_t)r * 1024 + k8] = ol;
}

__global__ __launch_bounds__(256) void prep_a0(const float* __restrict__ x0,
                                               const float* __restrict__ h0,
                                               const float* __restrict__ c0,
                                               u16* __restrict__ xhi, u16* __restrict__ xlo,
                                               u16* __restrict__ hhi, u16* __restrict__ hlo,
                                               float* __restrict__ cbuf) {
  int i = blockIdx.x * 256 + threadIdx.x;
  int sel = i >> 15, ii = i & 32767;
  int r = ii >> 7, k8 = (ii & 127) << 3;
  const float* s = (sel ? h0 : x0) + r * 1024 + k8;
  u16* hp = (sel ? hhi : xhi) + r * 1024 + k8;
  u16* lp = (sel ? hlo : xlo) + r * 1024 + k8;
  u16x8 oh, ol;
#pragma unroll
  for (int e = 0; e < 8; e++) {
    float f = s[e];
    u16 h = f2bf(f);
    oh[e] = h;
    ol[e] = f2bf(f - bf2f(h));
  }
  *(u16x8*)hp = oh;
  *(u16x8*)lp = ol;
  if (i < 32768) {
    float4 v0 = *(const float4*)&c0[i * 8];
    float4 v1 = *(const float4*)&c0[i * 8 + 4];
    *(float4*)&cbuf[i * 8] = v0;
    *(float4*)&cbuf[i * 8 + 4] = v1;
  }
}

__global__ __launch_bounds__(256) void prep_bias(const float* __restrict__ Wih,
                                                 const float* __restrict__ b_ih,
                                                 const float* __restrict__ b_hh,
                                                 const float* __restrict__ b_lin,
                                                 float* __restrict__ bc0,
                                                 float* __restrict__ bc1) {
  int wid = threadIdx.x >> 6, lane = threadIdx.x & 63;
  int R = blockIdx.x * 4 + wid;
  int o = origR2(R);
  float p = 0.f;
#pragma unroll
  for (int it = 0; it < 16; it++) p += Wih[(size_t)o * 1024 + lane + it * 64] * b_lin[lane + it * 64];
#pragma unroll
  for (int m = 1; m < 64; m <<= 1) p += __shfl_xor(p, m);
  if (lane == 0) {
    float s = b_ih[o] + b_hh[o];
    bc0[R] = s;
    bc1[R] = s + p;
  }
}

// Normalize in place using precomputed stats (S at stats[0..131071],
// S2 at stats[131072..]). Block = (t, b-half); thread owns 4 d's (float4 rows).
__global__ __launch_bounds__(256) void bn_norm(const float* __restrict__ stats,
                                               float* __restrict__ out) {
  int t = blockIdx.x >> 1, bh = blockIdx.x & 1;
  int d = threadIdx.x << 2;
  const float* sp = stats + t * 1024 + d;
  const float* sp2 = stats + 131072 + t * 1024 + d;
  float mean[4], rs[4];
#pragma unroll
  for (int e = 0; e < 4; e++) {
    float mn = sp[e] * (1.f / 256.f);
    float var = fmaxf(sp2[e] * (1.f / 256.f) - mn * mn, 0.f);
    mean[e] = mn;
    rs[e] = rsqrtf(var + 1e-5f);
  }
  float* base = out + (size_t)t * 262144 + bh * 131072 + d;
#pragma unroll 4
  for (int b = 0; b < 128; b++) {
    float4 v = *(float4*)(base + b * 1024);
    v.x = (v.x - mean[0]) * rs[0];
    v.y = (v.y - mean[1]) * rs[1];
    v.z = (v.z - mean[2]) * rs[2];
    v.w = (v.w - mean[3]) * rs[3];
    *(float4*)(base + b * 1024) = v;
  }
}

extern "C" void kernel_launch(void* const* d_in, const int* in_sizes, int n_in,
                              void* d_out, int out_size, void* d_ws, size_t ws_size,
                              hipStream_t stream) {
  const float* inputs = (const float*)d_in[0];
  const float* W_ih = (const float*)d_in[1];
  const float* W_hh = (const float*)d_in[2];
  const float* b_ih = (const float*)d_in[3];
  const float* b_hh = (const float*)d_in[4];
  const float* W_lin = (const float*)d_in[5];
  const float* b_lin = (const float*)d_in[6];
  const float* h0 = (const float*)d_in[7];
  const float* c0 = (const float*)d_in[8];
  float* out = (float*)d_out;

  char* ws = (char*)d_ws;
  float* bc0 = (float*)(ws + 0);             // 16,384
  float* bc1 = (float*)(ws + 16384);         // 16,384
  float* cbuf = (float*)(ws + 32768);        // 1,048,576
  u16* Wlin_hi = (u16*)(ws + 1081344);       // 2,097,152
  u16* Beff_hi = (u16*)(ws + 3178496);       // 8,388,608
  u16* Beff_lo = (u16*)(ws + 11567104);      // 8,388,608
  u16* xhi = (u16*)(ws + 19955712);          // 524,288
  u16* xlo = (u16*)(ws + 20480000);          // 524,288
  u16* h0hi = (u16*)(ws + 21004288);         // 524,288
  u16* h0lo = (u16*)(ws + 21528576);         // 524,288
  u16* Hlo0 = (u16*)(ws + 22052864);         // 524,288
  u16* Hlo1 = (u16*)(ws + 22577152);         // 524,288
  u16* Hhi = (u16*)(ws + 23101440);          // 67,108,864 (128 slabs of 512KB)
  // transients aliased inside Hhi (dead after prep / step 0):
  u16* Whh_hi = (u16*)(ws + 23101440 + 2097152);    // slabs 4..19
  u16* Whh_lo = (u16*)(ws + 23101440 + 10485760);   // slabs 20..35
  u16* Wih_hi = (u16*)(ws + 23101440 + 18874368);   // slabs 36..51
  u16* Wih_lo = (u16*)(ws + 23101440 + 27262976);   // slabs 52..67
  u16* Wlt_hi = (u16*)(ws + 23101440 + 35651584);   // slabs 68..71
  u16* Wlt_lo = (u16*)(ws + 23101440 + 37748736);   // slabs 72..75
  float* Wc_f32 = (float*)(ws + 23101440 + 39845888);  // slabs 76..107
  float* stats = (float*)(ws + 90210304);    // 1,048,576 (S | S2), after Hhi

  hipMemsetAsync(stats, 0, 1048576, stream);
  prep_split<true, true><<<2048, 256, 0, stream>>>(W_ih, Wih_hi, Wih_lo);
  prep_split<true, true><<<2048, 256, 0, stream>>>(W_hh, Whh_hi, Whh_lo);
  prep_split<false, false><<<512, 256, 0, stream>>>(W_lin, Wlin_hi, nullptr);
  prep_wlt<<<512, 256, 0, stream>>>(W_lin, Wlt_hi, Wlt_lo);
  prep_a0<<<256, 256, 0, stream>>>(inputs, h0, c0, xhi, xlo, h0hi, h0lo, cbuf);
  prep_bias<<<1024, 256, 0, stream>>>(W_ih, b_ih, b_hh, b_lin, bc0, bc1);

  // W_c = W_ih @ W_lin (bf16x3), rows interleaved. M=4096, N=1024, K=1024.
  gemmk<64, 64, 16, 0, 0, 0, 16><<<1024, 256, 0, stream>>>(
      Wih_hi, Wih_lo, nullptr, nullptr, Wlt_hi, Wlt_lo, nullptr, nullptr,
      nullptr, nullptr, nullptr, nullptr, Wc_f32);
  prep_beff<<<2048, 256, 0, stream>>>(Wc_f32, W_hh, Beff_hi, Beff_lo);

  // step 0: gates from (x0,h0): two K-phases (x @ Wih, h @ Whh), K=2048 total.
  gemmk<64, 64, 32, 1, 1, 1, 0><<<256, 256, 0, stream>>>(
      xhi, xlo, h0hi, h0lo, Wih_hi, Wih_lo, Whh_hi, Whh_lo,
      bc0, cbuf, Hhi, Hlo0, nullptr);
  // steps 1..127: gates = h_{t-1} @ Beff^T (bf16x3 joint staging), K=1024.
  for (int t = 1; t < 128; t++) {
    gemmk<64, 64, 16, 0, 1, 1, 0><<<256, 256, 0, stream>>>(
        Hhi + (size_t)(t - 1) * SLABH, ((t - 1) & 1) ? Hlo1 : Hlo0, nullptr, nullptr,
        Beff_hi, Beff_lo, nullptr, nullptr,
        bc1, cbuf, Hhi + (size_t)t * SLABH, (t & 1) ? Hlo1 : Hlo0, nullptr);
  }

  // ys' = Hs_hi @ W_lin_hi^T (no bias: b_lin cancels in BN). M=32768, N=1024.
  // Epilogue accumulates per-(t,d) sum/sumsq into stats via atomics.
  gemmk<128, 128, 16, 2, 3, 3, 0><<<2048, 256, 0, stream>>>(
      Hhi, nullptr, nullptr, nullptr, Wlin_hi, nullptr, nullptr, nullptr,
      nullptr, stats, nullptr, nullptr, out);
  bn_norm<<<256, 256, 0, stream>>>(stats, out);
}